// Round 2
// baseline (333.740 us; speedup 1.0000x reference)
//
#include <hip/hip_runtime.h>
#include <stdint.h>

// SoftmaxAttention: x[2,2048,2048] f32, w_qkv[6144,2048] f32, w_out[2048,2048] f32
// out[2,2048,2048] f32.  All matmul-shaped compute via bf16 MFMA 16x16x32.

typedef __attribute__((ext_vector_type(8))) short bf16x8;
typedef __attribute__((ext_vector_type(8))) unsigned short u16x8;
typedef __attribute__((ext_vector_type(4))) unsigned short u16x4;
typedef __attribute__((ext_vector_type(4))) float f32x4;
typedef unsigned short ushort_t;

#define MFMA16(a, b, c) __builtin_amdgcn_mfma_f32_16x16x32_bf16((a), (b), (c), 0, 0, 0)

__device__ __forceinline__ unsigned short f2bf(float f) {
  union { float f; uint32_t u; } v; v.f = f;
  uint32_t r = v.u + 0x7FFFu + ((v.u >> 16) & 1u);  // RNE
  return (unsigned short)(r >> 16);
}

__device__ __forceinline__ void gld_lds16(const unsigned short* g, unsigned short* lds) {
  __builtin_amdgcn_global_load_lds(
      (const __attribute__((address_space(1))) void*)g,
      (__attribute__((address_space(3))) void*)lds, 16, 0, 0);
}

__device__ __forceinline__ void sbar() {
  __builtin_amdgcn_sched_barrier(0);
  __builtin_amdgcn_s_barrier();
  __builtin_amdgcn_sched_barrier(0);
}

// ---------------------------------------------------------------- cvt f32->bf16
__global__ __launch_bounds__(256) void cvt_bf16(const float* __restrict__ in,
                                                unsigned short* __restrict__ out, int n8) {
  int stride = gridDim.x * blockDim.x;
  for (int i = blockIdx.x * blockDim.x + threadIdx.x; i < n8; i += stride) {
    float4 a = reinterpret_cast<const float4*>(in)[i * 2];
    float4 b = reinterpret_cast<const float4*>(in)[i * 2 + 1];
    u16x8 o;
    o[0] = f2bf(a.x); o[1] = f2bf(a.y); o[2] = f2bf(a.z); o[3] = f2bf(a.w);
    o[4] = f2bf(b.x); o[5] = f2bf(b.y); o[6] = f2bf(b.z); o[7] = f2bf(b.w);
    reinterpret_cast<u16x8*>(out)[i] = o;
  }
}

// ===================== 256x256 8-phase double-buffered GEMM (QKV) =============
// A = xb [4096,2048], Bt = wqkvb [6144,2048], K = 2048 (NT = 32 K-tiles of 64).
// LDS: A[2 dbuf][2 ksub][256 rows][32 k] bf16 (+ same for B) = 128 KiB.
// 8 waves = 2(M) x 4(N); per-wave output 128x64 = acc[8][4] f32x4.
// Phase = (ksub, mgroup): ds_read frags + stage 1 half-tile + bar + lgkm0 +
// 16 MFMA + [vmcnt(8)] + bar.  Counted vmcnt: 4 half-tiles (8 insts) in flight.
#define QNT 32

#define STG_A(DBUF, KSS, KOFF)                                                  \
  do { gld_lds16(gA0 + (KOFF), lA + ((DBUF)*2 + (KSS)) * 8192 + tid * 8);       \
       gld_lds16(gA1 + (KOFF), lA + ((DBUF)*2 + (KSS)) * 8192 + 4096 + tid * 8); } while (0)
#define STG_B(DBUF, KSS, KOFF)                                                  \
  do { gld_lds16(gB0 + (KOFF), lB + ((DBUF)*2 + (KSS)) * 8192 + tid * 8);       \
       gld_lds16(gB1 + (KOFF), lB + ((DBUF)*2 + (KSS)) * 8192 + 4096 + tid * 8); } while (0)

#define PH(BUF, KS, MG, STAGE_STMT, WAIT_STMT)                                  \
  {                                                                             \
    const unsigned short* lab = lA + ((BUF) * 2 + (KS)) * 8192;                 \
    const unsigned short* lbb = lB + ((BUF) * 2 + (KS)) * 8192;                 \
    bf16x8 af_[4];                                                              \
    _Pragma("unroll") for (int mf = 0; mf < 4; ++mf)                            \
      af_[mf] = *(const bf16x8*)&lab[(wm * 128 + (MG) * 64 + mf * 16 + lm) * 32 + k8]; \
    if ((MG) == 0) {                                                            \
      _Pragma("unroll") for (int nf = 0; nf < 4; ++nf)                          \
        bfr[nf] = *(const bf16x8*)&lbb[(wn * 64 + nf * 16 + lm) * 32 + k8];     \
    }                                                                           \
    STAGE_STMT;                                                                 \
    sbar();                                                                     \
    asm volatile("s_waitcnt lgkmcnt(0)" ::: "memory");                          \
    __builtin_amdgcn_sched_barrier(0);                                          \
    __builtin_amdgcn_s_setprio(1);                                              \
    _Pragma("unroll") for (int mf = 0; mf < 4; ++mf)                            \
      _Pragma("unroll") for (int nf = 0; nf < 4; ++nf)                          \
        acc[(MG) * 4 + mf][nf] = MFMA16(af_[mf], bfr[nf], acc[(MG) * 4 + mf][nf]); \
    __builtin_amdgcn_s_setprio(0);                                              \
    WAIT_STMT;                                                                  \
    sbar();                                                                     \
  }

#define WV8 asm volatile("s_waitcnt vmcnt(8)" ::: "memory")
#define WV4 asm volatile("s_waitcnt vmcnt(4)" ::: "memory")
#define WV0 asm volatile("s_waitcnt vmcnt(0)" ::: "memory")
#define NOPST ((void)0)

__global__ __launch_bounds__(512, 2) void gemm_qkv8(const unsigned short* __restrict__ xb,
                                                    const unsigned short* __restrict__ wqb,
                                                    unsigned short* __restrict__ Qb,
                                                    unsigned short* __restrict__ Kb,
                                                    unsigned short* __restrict__ Vtb) {
  __shared__ alignas(16) unsigned short lA[2 * 2 * 8192];  // 64 KiB
  __shared__ alignas(16) unsigned short lB[2 * 2 * 8192];  // 64 KiB

  // XCD-bijective swizzle: 384 blocks = 8 * 48
  const int bid = blockIdx.x;
  const int swz = (bid & 7) * 48 + (bid >> 3);
  const int bx = swz % 24, by = swz / 24;
  const int brow = by << 8, bcol = bx << 8;

  const int tid = threadIdx.x;
  const int l = tid & 63, w = tid >> 6;
  const int wm = w >> 2, wn = w & 3;
  const int lm = l & 15, k8 = 8 * (l >> 4);

  // staging source pointers (granule tid -> row tid>>2, k-granule tid&3)
  const int srow = tid >> 2;
  const int sk8 = (tid & 3) * 8;
  const unsigned short* gA0 = xb + (size_t)(brow + srow) * 2048 + sk8;
  const unsigned short* gA1 = xb + (size_t)(brow + 128 + srow) * 2048 + sk8;
  const unsigned short* gB0 = wqb + (size_t)(bcol + srow) * 2048 + sk8;
  const unsigned short* gB1 = wqb + (size_t)(bcol + 128 + srow) * 2048 + sk8;

  f32x4 acc[8][4];
#pragma unroll
  for (int i = 0; i < 8; ++i)
#pragma unroll
    for (int j = 0; j < 4; ++j) acc[i][j] = (f32x4){0.f, 0.f, 0.f, 0.f};
  bf16x8 bfr[4];

  // prologue: tiles 0 (k0,k1) and 1 (k0); wait for (0,k0); 12 insts issued
  STG_A(0, 0, 0);  STG_B(0, 0, 0);
  STG_A(0, 1, 32); STG_B(0, 1, 32);
  STG_A(1, 0, 64); STG_B(1, 0, 64);
  WV8;
  sbar();

  // main loop: t = 0 .. NT-3, full staging, vmcnt(8) every 2 phases
  for (int t = 0; t < QNT - 2; ++t) {
    const int buf = t & 1;
    PH(buf, 0, 0, STG_A(buf ^ 1, 1, (t + 1) * 64 + 32), NOPST);
    PH(buf, 0, 1, STG_B(buf ^ 1, 1, (t + 1) * 64 + 32), WV8);
    PH(buf, 1, 0, STG_A(buf, 0, (t + 2) * 64), NOPST);
    PH(buf, 1, 1, STG_B(buf, 0, (t + 2) * 64), WV8);
  }
  {  // t = NT-2: stage only (NT-1, k1); degrade waits 8 -> 4
    const int buf = (QNT - 2) & 1;
    PH(buf, 0, 0, STG_A(buf ^ 1, 1, (QNT - 1) * 64 + 32), NOPST);
    PH(buf, 0, 1, STG_B(buf ^ 1, 1, (QNT - 1) * 64 + 32), WV8);
    PH(buf, 1, 0, NOPST, NOPST);
    PH(buf, 1, 1, NOPST, WV4);
  }
  {  // t = NT-1: no staging; drain before k1
    const int buf = (QNT - 1) & 1;
    PH(buf, 0, 0, NOPST, NOPST);
    PH(buf, 0, 1, NOPST, WV0);
    PH(buf, 1, 0, NOPST, NOPST);
    PH(buf, 1, 1, NOPST, NOPST);
  }

  // epilogue: scatter Q,K -> [BH,T,128]; V -> [BH,128,T] (transposed)
  const int lr4 = (l >> 4) << 2;
#pragma unroll
  for (int mf = 0; mf < 8; ++mf) {
    const int trow = brow + wm * 128 + mf * 16 + lr4;  // 0..4095
    const int b_ = trow >> 11;
    const int t0 = trow & 2047;
#pragma unroll
    for (int nf = 0; nf < 4; ++nf) {
      const int c = bcol + wn * 64 + nf * 16 + lm;     // 0..6143
      const int which = c >> 11;                        // block-uniform
      const int cc = c & 2047;
      const int h = cc >> 7, d = cc & 127;
      const int bh = (b_ << 4) | h;
      if (which == 2) {
        u16x4 pk;
#pragma unroll
        for (int r = 0; r < 4; ++r) pk[r] = f2bf(acc[mf][nf][r]);
        *reinterpret_cast<u16x4*>(&Vtb[((size_t)bh * 128 + d) * 2048 + t0]) = pk;
      } else {
        unsigned short* dst = (which == 0 ? Qb : Kb) + ((size_t)bh * 2048 + t0) * 128 + d;
#pragma unroll
        for (int r = 0; r < 4; ++r) dst[(size_t)r * 128] = f2bf(acc[mf][nf][r]);
      }
    }
  }
}

// --------------------------------------------------- 128x128 bf16 GEMM core (B^T)
__device__ __forceinline__ void gemm128_core(const unsigned short* __restrict__ A,
                                             const unsigned short* __restrict__ Bt,
                                             int K, int brow, int bcol,
                                             unsigned short* lds_a, unsigned short* lds_b,
                                             f32x4 acc[4][4]) {
  const int tid = threadIdx.x;
  const int l   = tid & 63;
  const int w   = tid >> 6;
  const int wr  = (w >> 1) << 6;
  const int wc  = (w & 1) << 6;

  const int srow = tid >> 2;
  const int sswz = (tid & 3) ^ ((srow >> 1) & 3);
  const unsigned short* gA0 = A  + (size_t)(brow + srow) * K + 8 * sswz;
  const unsigned short* gA1 = gA0 + (size_t)64 * K;
  const unsigned short* gB0 = Bt + (size_t)(bcol + srow) * K + 8 * sswz;
  const unsigned short* gB1 = gB0 + (size_t)64 * K;

  unsigned short* la0 = lds_a + tid * 8;
  unsigned short* la1 = lds_a + (256 + tid) * 8;
  unsigned short* lb0 = lds_b + tid * 8;
  unsigned short* lb1 = lds_b + (256 + tid) * 8;

  const int fm    = l & 15;
  const int fswz8 = 8 * ((l >> 4) ^ ((fm >> 1) & 3));

  for (int k0 = 0; k0 < K; k0 += 32) {
    gld_lds16(gA0, la0);
    gld_lds16(gA1, la1);
    gld_lds16(gB0, lb0);
    gld_lds16(gB1, lb1);
    gA0 += 32; gA1 += 32; gB0 += 32; gB1 += 32;
    __syncthreads();
    bf16x8 af[4], bfv[4];
#pragma unroll
    for (int i = 0; i < 4; i++)
      af[i] = *(const bf16x8*)&lds_a[(wr + i * 16 + fm) * 32 + fswz8];
#pragma unroll
    for (int j = 0; j < 4; j++)
      bfv[j] = *(const bf16x8*)&lds_b[(wc + j * 16 + fm) * 32 + fswz8];
#pragma unroll
    for (int i = 0; i < 4; i++)
#pragma unroll
      for (int j = 0; j < 4; j++)
        acc[i][j] = MFMA16(af[i], bfv[j], acc[i][j]);
    __syncthreads();
  }
}

// -------------------------------------------------------------- output projection
__global__ __launch_bounds__(256) void gemm_out(const unsigned short* __restrict__ yb,
                                                const unsigned short* __restrict__ wob,
                                                float* __restrict__ out) {
  __shared__ alignas(16) unsigned short lds_a[128 * 32];
  __shared__ alignas(16) unsigned short lds_b[128 * 32];
  f32x4 acc[4][4];
#pragma unroll
  for (int i = 0; i < 4; i++)
#pragma unroll
    for (int j = 0; j < 4; j++) acc[i][j] = (f32x4){0.f, 0.f, 0.f, 0.f};

  const int brow = blockIdx.y << 7;
  const int bcol = blockIdx.x << 7;
  gemm128_core(yb, wob, 2048, brow, bcol, lds_a, lds_b, acc);

  const int l = threadIdx.x & 63;
  const int w = threadIdx.x >> 6;
  const int wr = (w >> 1) << 6, wc = (w & 1) << 6;
#pragma unroll
  for (int i = 0; i < 4; i++) {
    const int m0 = brow + wr + i * 16 + ((l >> 4) << 2);
#pragma unroll
    for (int j = 0; j < 4; j++) {
      const int n = bcol + wc + j * 16 + (l & 15);
#pragma unroll
      for (int r = 0; r < 4; r++) out[(size_t)(m0 + r) * 2048 + n] = acc[i][j][r];
    }
  }
}

// ------------------------------------------------------------------ flash attn
__global__ __launch_bounds__(256) void attn_kernel(const unsigned short* __restrict__ Qb,
                                                   const unsigned short* __restrict__ Kb,
                                                   const unsigned short* __restrict__ Vtb,
                                                   unsigned short* __restrict__ Yb) {
  __shared__ alignas(16) unsigned short lds_k[64 * 128];
  __shared__ alignas(16) unsigned short lds_v[128 * 64];
  __shared__ alignas(16) unsigned short p_lds[4][16 * 64];

  const int tid = threadIdx.x;
  const int l = tid & 63;
  const int w = tid >> 6;
  const int bh = blockIdx.y;
  const int b = bh >> 4, h = bh & 15;
  const float SC = 0.12752585f;  // log2(e)/sqrt(128)

  const unsigned short* Qg = Qb + (size_t)bh * 2048 * 128;
  const unsigned short* Kg = Kb + (size_t)bh * 2048 * 128;
  const unsigned short* Vg = Vtb + (size_t)bh * 128 * 2048;

  for (int ph = 0; ph < 2; ph++) {
    const int h64 = (ph == 0) ? (int)blockIdx.x : (31 - (int)blockIdx.x);
    const int q0 = h64 << 6;
    const int qw0 = q0 + (w << 4);

    bf16x8 qf[4];
#pragma unroll
    for (int ds = 0; ds < 4; ds++)
      qf[ds] = *(const bf16x8*)&Qg[(size_t)(qw0 + (l & 15)) * 128 + ds * 32 + 8 * (l >> 4)];

    f32x4 yacc[8];
#pragma unroll
    for (int dt = 0; dt < 8; dt++) yacc[dt] = (f32x4){0.f, 0.f, 0.f, 0.f};
    float mrow[4], lrow[4];
#pragma unroll
    for (int r = 0; r < 4; r++) { mrow[r] = -1e30f; lrow[r] = 0.f; }

    const int nkv = h64 + 1;
    for (int t = 0; t < nkv; t++) {
      const int kv0 = t << 6;
#pragma unroll
      for (int c = 0; c < 4; c++) {
        int s = c * 256 + tid;
        int row = s >> 4, g = s & 15;
        gld_lds16(&Kg[(size_t)(kv0 + row) * 128 + 8 * (g ^ (row & 7))], &lds_k[s * 8]);
      }
#pragma unroll
      for (int c = 0; c < 4; c++) {
        int s = c * 256 + tid;
        int row = s >> 3, g = s & 7;
        gld_lds16(&Vg[(size_t)row * 2048 + kv0 + 8 * (g ^ (row & 7))], &lds_v[s * 8]);
      }
      __syncthreads();

      if (kv0 <= qw0 + 15) {
        f32x4 sfr[4];
#pragma unroll
        for (int kt = 0; kt < 4; kt++) {
          const int kr = kt * 16 + (l & 15);
          f32x4 s4 = (f32x4){0.f, 0.f, 0.f, 0.f};
#pragma unroll
          for (int ds = 0; ds < 4; ds++) {
            bf16x8 kfr = *(const bf16x8*)&lds_k[kr * 128 + 8 * (((ds << 2) + (l >> 4)) ^ (kr & 7))];
            s4 = MFMA16(qf[ds], kfr, s4);
          }
          sfr[kt] = s4;
        }
        const bool need_mask = (kv0 + 63 > qw0);
#pragma unroll
        for (int kt = 0; kt < 4; kt++)
#pragma unroll
          for (int r = 0; r < 4; r++) {
            float sv = sfr[kt][r] * SC;
            if (need_mask) {
              int qa = qw0 + ((l >> 4) << 2) + r;
              int ka = kv0 + kt * 16 + (l & 15);
              sv = (ka > qa) ? -1e30f : sv;
            }
            sfr[kt][r] = sv;
          }
        float rmax, f[4], rsum[4];
#pragma unroll
        for (int r = 0; r < 4; r++) {
          rmax = fmaxf(fmaxf(sfr[0][r], sfr[1][r]), fmaxf(sfr[2][r], sfr[3][r]));
          rmax = fmaxf(rmax, __shfl_xor(rmax, 1));
          rmax = fmaxf(rmax, __shfl_xor(rmax, 2));
          rmax = fmaxf(rmax, __shfl_xor(rmax, 4));
          rmax = fmaxf(rmax, __shfl_xor(rmax, 8));
          float mn = fmaxf(mrow[r], rmax);
          f[r] = exp2f(mrow[r] - mn);
          mrow[r] = mn;
          rsum[r] = 0.f;
        }
#pragma unroll
        for (int kt = 0; kt < 4; kt++)
#pragma unroll
          for (int r = 0; r < 4; r++) {
            float p = exp2f(sfr[kt][r] - mrow[r]);
            rsum[r] += p;
            int row = ((l >> 4) << 2) + r;
            int k = kt * 16 + (l & 15);
            p_lds[w][row * 64 + (((k >> 3) ^ (row & 7)) << 3) + (k & 7)] = f2bf(p);
          }
#pragma unroll
        for (int r = 0; r < 4; r++) {
          float s = rsum[r];
          s += __shfl_xor(s, 1);
          s += __shfl_xor(s, 2);
          s += __shfl_xor(s, 4);
          s += __shfl_xor(s, 8);
          lrow[r] = lrow[r] * f[r] + s;
        }
#pragma unroll
        for (int dt = 0; dt < 8; dt++)
#pragma unroll
          for (int r = 0; r < 4; r++) yacc[dt][r] *= f[r];

        asm volatile("s_waitcnt lgkmcnt(0)" ::: "memory");
        __builtin_amdgcn_sched_barrier(0);

#pragma unroll
        for (int ks = 0; ks < 2; ks++) {
          const int prow = l & 15;
          bf16x8 pa = *(const bf16x8*)&p_lds[w][prow * 64 + ((((ks << 2) + (l >> 4)) ^ (prow & 7)) << 3)];
#pragma unroll
          for (int dt = 0; dt < 8; dt++) {
            const int d = dt * 16 + (l & 15);
            bf16x8 vb = *(const bf16x8*)&lds_v[d * 64 + ((((ks << 2) + (l >> 4)) ^ (d & 7)) << 3)];
            yacc[dt] = MFMA16(pa, vb, yacc[dt]);
          }
        }
      }
      __syncthreads();
    }
#pragma unroll
    for (int dt = 0; dt < 8; dt++)
#pragma unroll
      for (int r = 0; r < 4; r++) {
        int qa = qw0 + ((l >> 4) << 2) + r;
        Yb[((size_t)(b * 2048 + qa)) * 2048 + h * 128 + dt * 16 + (l & 15)] =
            f2bf(yacc[dt][r] / lrow[r]);
      }
  }
}

// ---------------------------------------------------------------------- launch
extern "C" void kernel_launch(void* const* d_in, const int* in_sizes, int n_in,
                              void* d_out, int out_size, void* d_ws, size_t ws_size,
                              hipStream_t stream) {
  const float* x    = (const float*)d_in[0];
  const float* wqkv = (const float*)d_in[1];
  const float* wout = (const float*)d_in[2];
  float* out = (float*)d_out;

  unsigned short* ws  = (unsigned short*)d_ws;
  unsigned short* xb  = ws;                        // 4096*2048
  unsigned short* wqb = xb + (size_t)8388608;      // 6144*2048
  unsigned short* wob = wqb + (size_t)12582912;    // 2048*2048
  unsigned short* Qb  = wob + (size_t)4194304;     // [32,2048,128]
  unsigned short* Kb  = Qb + (size_t)8388608;      // [32,2048,128]
  unsigned short* Vtb = Kb + (size_t)8388608;      // [32,128,2048]
  unsigned short* Yb  = Vtb + (size_t)8388608;     // [4096,2048]

  cvt_bf16<<<1024, 256, 0, stream>>>(x, xb, 8388608 / 8);
  cvt_bf16<<<1024, 256, 0, stream>>>(wqkv, wqb, 12582912 / 8);
  cvt_bf16<<<512, 256, 0, stream>>>(wout, wob, 4194304 / 8);
  gemm_qkv8<<<384, 512, 0, stream>>>(xb, wqb, Qb, Kb, Vtb);
  attn_kernel<<<dim3(16, 32), 256, 0, stream>>>(Qb, Kb, Vtb, Yb);
  gemm_out<<<dim3(16, 32), 256, 0, stream>>>(Yb, wob, out);
}

// Round 3
// 327.600 us; speedup vs baseline: 1.0187x; 1.0187x over previous
//
#include <hip/hip_runtime.h>
#include <stdint.h>

// SoftmaxAttention: x[2,2048,2048] f32, w_qkv[6144,2048] f32, w_out[2048,2048] f32
// out[2,2048,2048] f32.  All matmul-shaped compute via bf16 MFMA 16x16x32.

typedef __attribute__((ext_vector_type(8))) short bf16x8;
typedef __attribute__((ext_vector_type(8))) unsigned short u16x8;
typedef __attribute__((ext_vector_type(4))) unsigned short u16x4;
typedef __attribute__((ext_vector_type(4))) float f32x4;

#define MFMA16(a, b, c) __builtin_amdgcn_mfma_f32_16x16x32_bf16((a), (b), (c), 0, 0, 0)

__device__ __forceinline__ unsigned short f2bf(float f) {
  union { float f; uint32_t u; } v; v.f = f;
  uint32_t r = v.u + 0x7FFFu + ((v.u >> 16) & 1u);  // RNE
  return (unsigned short)(r >> 16);
}

__device__ __forceinline__ void gld_lds16(const unsigned short* g, unsigned short* lds) {
  __builtin_amdgcn_global_load_lds(
      (const __attribute__((address_space(1))) void*)g,
      (__attribute__((address_space(3))) void*)lds, 16, 0, 0);
}

__device__ __forceinline__ void sbar() {
  __builtin_amdgcn_sched_barrier(0);
  __builtin_amdgcn_s_barrier();
  __builtin_amdgcn_sched_barrier(0);
}

// ---------------------------------------------------------------- cvt f32->bf16
__global__ __launch_bounds__(256) void cvt_bf16(const float* __restrict__ in,
                                                unsigned short* __restrict__ out, int n8) {
  int stride = gridDim.x * blockDim.x;
  for (int i = blockIdx.x * blockDim.x + threadIdx.x; i < n8; i += stride) {
    float4 a = reinterpret_cast<const float4*>(in)[i * 2];
    float4 b = reinterpret_cast<const float4*>(in)[i * 2 + 1];
    u16x8 o;
    o[0] = f2bf(a.x); o[1] = f2bf(a.y); o[2] = f2bf(a.z); o[3] = f2bf(a.w);
    o[4] = f2bf(b.x); o[5] = f2bf(b.y); o[6] = f2bf(b.z); o[7] = f2bf(b.w);
    reinterpret_cast<u16x8*>(out)[i] = o;
  }
}

// ===================== 256x256 8-phase double-buffered GEMM (QKV) =============
// A = xb [4096,2048], Bt = wqkvb [6144,2048], K = 2048 (NT = 32 K-tiles of 64).
// LDS: A[2 dbuf][2 ksub][256 rows][32 k] bf16 (+ same for B) = 128 KiB.
// T2 swizzle: LDS[row][g] holds global k-granule g ^ ((row>>1)&3); linear dest
// + pre-swizzled global source (rule #21), fragment reads XOR the same term.
#define QNT 32

#define STG_A(DBUF, KSS, KOFF)                                                  \
  do { gld_lds16(gA0 + (KOFF), lA + ((DBUF)*2 + (KSS)) * 8192 + tid * 8);       \
       gld_lds16(gA1 + (KOFF), lA + ((DBUF)*2 + (KSS)) * 8192 + 4096 + tid * 8); } while (0)
#define STG_B(DBUF, KSS, KOFF)                                                  \
  do { gld_lds16(gB0 + (KOFF), lB + ((DBUF)*2 + (KSS)) * 8192 + tid * 8);       \
       gld_lds16(gB1 + (KOFF), lB + ((DBUF)*2 + (KSS)) * 8192 + 4096 + tid * 8); } while (0)

#define PH(BUF, KS, MG, STAGE_STMT, WAIT_STMT)                                  \
  {                                                                             \
    const unsigned short* lab = lA + ((BUF) * 2 + (KS)) * 8192;                 \
    const unsigned short* lbb = lB + ((BUF) * 2 + (KS)) * 8192;                 \
    bf16x8 af_[4];                                                              \
    _Pragma("unroll") for (int mf = 0; mf < 4; ++mf)                            \
      af_[mf] = *(const bf16x8*)&lab[(wm * 128 + (MG) * 64 + mf * 16 + lm) * 32 + k8]; \
    if ((MG) == 0) {                                                            \
      _Pragma("unroll") for (int nf = 0; nf < 4; ++nf)                          \
        bfr[nf] = *(const bf16x8*)&lbb[(wn * 64 + nf * 16 + lm) * 32 + k8];     \
    }                                                                           \
    STAGE_STMT;                                                                 \
    sbar();                                                                     \
    asm volatile("s_waitcnt lgkmcnt(0)" ::: "memory");                          \
    __builtin_amdgcn_sched_barrier(0);                                          \
    __builtin_amdgcn_s_setprio(1);                                              \
    _Pragma("unroll") for (int mf = 0; mf < 4; ++mf)                            \
      _Pragma("unroll") for (int nf = 0; nf < 4; ++nf)                          \
        acc[(MG) * 4 + mf][nf] = MFMA16(af_[mf], bfr[nf], acc[(MG) * 4 + mf][nf]); \
    __builtin_amdgcn_s_setprio(0);                                              \
    WAIT_STMT;                                                                  \
    sbar();                                                                     \
  }

#define WV8 asm volatile("s_waitcnt vmcnt(8)" ::: "memory")
#define WV4 asm volatile("s_waitcnt vmcnt(4)" ::: "memory")
#define WV0 asm volatile("s_waitcnt vmcnt(0)" ::: "memory")
#define NOPST ((void)0)

__global__ __launch_bounds__(512, 2) void gemm_qkv8(const unsigned short* __restrict__ xb,
                                                    const unsigned short* __restrict__ wqb,
                                                    unsigned short* __restrict__ Qb,
                                                    unsigned short* __restrict__ Kb,
                                                    unsigned short* __restrict__ Vtb) {
  __shared__ alignas(16) unsigned short lA[2 * 2 * 8192];  // 64 KiB
  __shared__ alignas(16) unsigned short lB[2 * 2 * 8192];  // 64 KiB

  // XCD-bijective 2D chunking: grid 16(by) x 24(bx); XCD gets an 8x6 chunk
  // (footprint A 8MB + B 6MB instead of 2MB + 24MB).
  const int bid = blockIdx.x;
  const int xcd = bid & 7;
  const int loc = bid >> 3;                 // 0..47
  const int by = (xcd >> 2) * 8 + loc / 6;  // 0..15
  const int bx = (xcd & 3) * 6 + loc % 6;   // 0..23
  const int brow = by << 8, bcol = bx << 8;

  const int tid = threadIdx.x;
  const int l = tid & 63, w = tid >> 6;
  const int wm = w >> 2, wn = w & 3;
  const int lm = l & 15;
  // T2 read-side swizzle (2-way max = free): granule = (l>>4) ^ ((lm>>1)&3)
  const int k8 = 8 * ((l >> 4) ^ ((lm >> 1) & 3));

  // staging: dest is LINEAR (row = tid>>2, granule = tid&3); source granule
  // pre-swizzled by the same involution so LDS[row][g] = global g^((row>>1)&3)
  const int srow = tid >> 2;
  const int sk8 = 8 * ((tid & 3) ^ ((srow >> 1) & 3));
  const unsigned short* gA0 = xb + (size_t)(brow + srow) * 2048 + sk8;
  const unsigned short* gA1 = xb + (size_t)(brow + 128 + srow) * 2048 + sk8;
  const unsigned short* gB0 = wqb + (size_t)(bcol + srow) * 2048 + sk8;
  const unsigned short* gB1 = wqb + (size_t)(bcol + 128 + srow) * 2048 + sk8;

  f32x4 acc[8][4];
#pragma unroll
  for (int i = 0; i < 8; ++i)
#pragma unroll
    for (int j = 0; j < 4; ++j) acc[i][j] = (f32x4){0.f, 0.f, 0.f, 0.f};
  bf16x8 bfr[4];

  // prologue: tiles 0 (k0,k1) and 1 (k0); wait for (0,k0)
  STG_A(0, 0, 0);  STG_B(0, 0, 0);
  STG_A(0, 1, 32); STG_B(0, 1, 32);
  STG_A(1, 0, 64); STG_B(1, 0, 64);
  WV8;
  sbar();

  for (int t = 0; t < QNT - 2; ++t) {
    const int buf = t & 1;
    PH(buf, 0, 0, STG_A(buf ^ 1, 1, (t + 1) * 64 + 32), NOPST);
    PH(buf, 0, 1, STG_B(buf ^ 1, 1, (t + 1) * 64 + 32), WV8);
    PH(buf, 1, 0, STG_A(buf, 0, (t + 2) * 64), NOPST);
    PH(buf, 1, 1, STG_B(buf, 0, (t + 2) * 64), WV8);
  }
  {  // t = NT-2
    const int buf = (QNT - 2) & 1;
    PH(buf, 0, 0, STG_A(buf ^ 1, 1, (QNT - 1) * 64 + 32), NOPST);
    PH(buf, 0, 1, STG_B(buf ^ 1, 1, (QNT - 1) * 64 + 32), WV8);
    PH(buf, 1, 0, NOPST, NOPST);
    PH(buf, 1, 1, NOPST, WV4);
  }
  {  // t = NT-1
    const int buf = (QNT - 1) & 1;
    PH(buf, 0, 0, NOPST, NOPST);
    PH(buf, 0, 1, NOPST, WV0);
    PH(buf, 1, 0, NOPST, NOPST);
    PH(buf, 1, 1, NOPST, NOPST);
  }

  // epilogue: scatter Q,K -> [BH,T,128]; V -> [BH,128,T] (transposed)
  const int lr4 = (l >> 4) << 2;
#pragma unroll
  for (int mf = 0; mf < 8; ++mf) {
    const int trow = brow + wm * 128 + mf * 16 + lr4;  // 0..4095
    const int b_ = trow >> 11;
    const int t0 = trow & 2047;
#pragma unroll
    for (int nf = 0; nf < 4; ++nf) {
      const int c = bcol + wn * 64 + nf * 16 + lm;     // 0..6143
      const int which = c >> 11;                        // block-uniform
      const int cc = c & 2047;
      const int h = cc >> 7, d = cc & 127;
      const int bh = (b_ << 4) | h;
      if (which == 2) {
        u16x4 pk;
#pragma unroll
        for (int r = 0; r < 4; ++r) pk[r] = f2bf(acc[mf][nf][r]);
        *reinterpret_cast<u16x4*>(&Vtb[((size_t)bh * 128 + d) * 2048 + t0]) = pk;
      } else {
        unsigned short* dst = (which == 0 ? Qb : Kb) + ((size_t)bh * 2048 + t0) * 128 + d;
#pragma unroll
        for (int r = 0; r < 4; ++r) dst[(size_t)r * 128] = f2bf(acc[mf][nf][r]);
      }
    }
  }
}

// --------------------------------------------------- 128x128 bf16 GEMM core (B^T)
__device__ __forceinline__ void gemm128_core(const unsigned short* __restrict__ A,
                                             const unsigned short* __restrict__ Bt,
                                             int K, int brow, int bcol,
                                             unsigned short* lds_a, unsigned short* lds_b,
                                             f32x4 acc[4][4]) {
  const int tid = threadIdx.x;
  const int l   = tid & 63;
  const int w   = tid >> 6;
  const int wr  = (w >> 1) << 6;
  const int wc  = (w & 1) << 6;

  const int srow = tid >> 2;
  const int sswz = (tid & 3) ^ ((srow >> 1) & 3);
  const unsigned short* gA0 = A  + (size_t)(brow + srow) * K + 8 * sswz;
  const unsigned short* gA1 = gA0 + (size_t)64 * K;
  const unsigned short* gB0 = Bt + (size_t)(bcol + srow) * K + 8 * sswz;
  const unsigned short* gB1 = gB0 + (size_t)64 * K;

  unsigned short* la0 = lds_a + tid * 8;
  unsigned short* la1 = lds_a + (256 + tid) * 8;
  unsigned short* lb0 = lds_b + tid * 8;
  unsigned short* lb1 = lds_b + (256 + tid) * 8;

  const int fm    = l & 15;
  const int fswz8 = 8 * ((l >> 4) ^ ((fm >> 1) & 3));

  for (int k0 = 0; k0 < K; k0 += 32) {
    gld_lds16(gA0, la0);
    gld_lds16(gA1, la1);
    gld_lds16(gB0, lb0);
    gld_lds16(gB1, lb1);
    gA0 += 32; gA1 += 32; gB0 += 32; gB1 += 32;
    __syncthreads();
    bf16x8 af[4], bfv[4];
#pragma unroll
    for (int i = 0; i < 4; i++)
      af[i] = *(const bf16x8*)&lds_a[(wr + i * 16 + fm) * 32 + fswz8];
#pragma unroll
    for (int j = 0; j < 4; j++)
      bfv[j] = *(const bf16x8*)&lds_b[(wc + j * 16 + fm) * 32 + fswz8];
#pragma unroll
    for (int i = 0; i < 4; i++)
#pragma unroll
      for (int j = 0; j < 4; j++)
        acc[i][j] = MFMA16(af[i], bfv[j], acc[i][j]);
    __syncthreads();
  }
}

// -------------------------------------------------------------- output projection
__global__ __launch_bounds__(256) void gemm_out(const unsigned short* __restrict__ yb,
                                                const unsigned short* __restrict__ wob,
                                                float* __restrict__ out) {
  __shared__ alignas(16) unsigned short lds_a[128 * 32];
  __shared__ alignas(16) unsigned short lds_b[128 * 32];
  f32x4 acc[4][4];
#pragma unroll
  for (int i = 0; i < 4; i++)
#pragma unroll
    for (int j = 0; j < 4; j++) acc[i][j] = (f32x4){0.f, 0.f, 0.f, 0.f};

  const int brow = blockIdx.y << 7;
  const int bcol = blockIdx.x << 7;
  gemm128_core(yb, wob, 2048, brow, bcol, lds_a, lds_b, acc);

  const int l = threadIdx.x & 63;
  const int w = threadIdx.x >> 6;
  const int wr = (w >> 1) << 6, wc = (w & 1) << 6;
#pragma unroll
  for (int i = 0; i < 4; i++) {
    const int m0 = brow + wr + i * 16 + ((l >> 4) << 2);
#pragma unroll
    for (int j = 0; j < 4; j++) {
      const int n = bcol + wc + j * 16 + (l & 15);
#pragma unroll
      for (int r = 0; r < 4; r++) out[(size_t)(m0 + r) * 2048 + n] = acc[i][j][r];
    }
  }
}

// ------------------------------------------------------------------ flash attn
__global__ __launch_bounds__(256) void attn_kernel(const unsigned short* __restrict__ Qb,
                                                   const unsigned short* __restrict__ Kb,
                                                   const unsigned short* __restrict__ Vtb,
                                                   unsigned short* __restrict__ Yb) {
  __shared__ alignas(16) unsigned short lds_k[64 * 128];
  __shared__ alignas(16) unsigned short lds_v[128 * 64];
  __shared__ alignas(16) unsigned short p_lds[4][16 * 64];

  const int tid = threadIdx.x;
  const int l = tid & 63;
  const int w = tid >> 6;
  const int bh = blockIdx.y;
  const int b = bh >> 4, h = bh & 15;
  const float SC = 0.12752585f;  // log2(e)/sqrt(128)

  const unsigned short* Qg = Qb + (size_t)bh * 2048 * 128;
  const unsigned short* Kg = Kb + (size_t)bh * 2048 * 128;
  const unsigned short* Vg = Vtb + (size_t)bh * 128 * 2048;

  for (int ph = 0; ph < 2; ph++) {
    const int h64 = (ph == 0) ? (int)blockIdx.x : (31 - (int)blockIdx.x);
    const int q0 = h64 << 6;
    const int qw0 = q0 + (w << 4);

    bf16x8 qf[4];
#pragma unroll
    for (int ds = 0; ds < 4; ds++)
      qf[ds] = *(const bf16x8*)&Qg[(size_t)(qw0 + (l & 15)) * 128 + ds * 32 + 8 * (l >> 4)];

    f32x4 yacc[8];
#pragma unroll
    for (int dt = 0; dt < 8; dt++) yacc[dt] = (f32x4){0.f, 0.f, 0.f, 0.f};
    float mrow[4], lrow[4];
#pragma unroll
    for (int r = 0; r < 4; r++) { mrow[r] = -1e30f; lrow[r] = 0.f; }

    const int nkv = h64 + 1;
    for (int t = 0; t < nkv; t++) {
      const int kv0 = t << 6;
#pragma unroll
      for (int c = 0; c < 4; c++) {
        int s = c * 256 + tid;
        int row = s >> 4, g = s & 15;
        gld_lds16(&Kg[(size_t)(kv0 + row) * 128 + 8 * (g ^ (row & 7))], &lds_k[s * 8]);
      }
#pragma unroll
      for (int c = 0; c < 4; c++) {
        int s = c * 256 + tid;
        int row = s >> 3, g = s & 7;
        gld_lds16(&Vg[(size_t)row * 2048 + kv0 + 8 * (g ^ (row & 7))], &lds_v[s * 8]);
      }
      __syncthreads();

      if (kv0 <= qw0 + 15) {
        f32x4 sfr[4];
#pragma unroll
        for (int kt = 0; kt < 4; kt++) {
          const int kr = kt * 16 + (l & 15);
          f32x4 s4 = (f32x4){0.f, 0.f, 0.f, 0.f};
#pragma unroll
          for (int ds = 0; ds < 4; ds++) {
            bf16x8 kfr = *(const bf16x8*)&lds_k[kr * 128 + 8 * (((ds << 2) + (l >> 4)) ^ (kr & 7))];
            s4 = MFMA16(qf[ds], kfr, s4);
          }
          sfr[kt] = s4;
        }
        const bool need_mask = (kv0 + 63 > qw0);
#pragma unroll
        for (int kt = 0; kt < 4; kt++)
#pragma unroll
          for (int r = 0; r < 4; r++) {
            float sv = sfr[kt][r] * SC;
            if (need_mask) {
              int qa = qw0 + ((l >> 4) << 2) + r;
              int ka = kv0 + kt * 16 + (l & 15);
              sv = (ka > qa) ? -1e30f : sv;
            }
            sfr[kt][r] = sv;
          }
        float rmax, f[4], rsum[4];
#pragma unroll
        for (int r = 0; r < 4; r++) {
          rmax = fmaxf(fmaxf(sfr[0][r], sfr[1][r]), fmaxf(sfr[2][r], sfr[3][r]));
          rmax = fmaxf(rmax, __shfl_xor(rmax, 1));
          rmax = fmaxf(rmax, __shfl_xor(rmax, 2));
          rmax = fmaxf(rmax, __shfl_xor(rmax, 4));
          rmax = fmaxf(rmax, __shfl_xor(rmax, 8));
          float mn = fmaxf(mrow[r], rmax);
          f[r] = exp2f(mrow[r] - mn);
          mrow[r] = mn;
          rsum[r] = 0.f;
        }
#pragma unroll
        for (int kt = 0; kt < 4; kt++)
#pragma unroll
          for (int r = 0; r < 4; r++) {
            float p = exp2f(sfr[kt][r] - mrow[r]);
            rsum[r] += p;
            int row = ((l >> 4) << 2) + r;
            int k = kt * 16 + (l & 15);
            p_lds[w][row * 64 + (((k >> 3) ^ (row & 7)) << 3) + (k & 7)] = f2bf(p);
          }
#pragma unroll
        for (int r = 0; r < 4; r++) {
          float s = rsum[r];
          s += __shfl_xor(s, 1);
          s += __shfl_xor(s, 2);
          s += __shfl_xor(s, 4);
          s += __shfl_xor(s, 8);
          lrow[r] = lrow[r] * f[r] + s;
        }
#pragma unroll
        for (int dt = 0; dt < 8; dt++)
#pragma unroll
          for (int r = 0; r < 4; r++) yacc[dt][r] *= f[r];

        asm volatile("s_waitcnt lgkmcnt(0)" ::: "memory");
        __builtin_amdgcn_sched_barrier(0);

#pragma unroll
        for (int ks = 0; ks < 2; ks++) {
          const int prow = l & 15;
          bf16x8 pa = *(const bf16x8*)&p_lds[w][prow * 64 + ((((ks << 2) + (l >> 4)) ^ (prow & 7)) << 3)];
#pragma unroll
          for (int dt = 0; dt < 8; dt++) {
            const int d = dt * 16 + (l & 15);
            bf16x8 vb = *(const bf16x8*)&lds_v[d * 64 + ((((ks << 2) + (l >> 4)) ^ (d & 7)) << 3)];
            yacc[dt] = MFMA16(pa, vb, yacc[dt]);
          }
        }
      }
      __syncthreads();
    }
#pragma unroll
    for (int dt = 0; dt < 8; dt++)
#pragma unroll
      for (int r = 0; r < 4; r++) {
        int qa = qw0 + ((l >> 4) << 2) + r;
        Yb[((size_t)(b * 2048 + qa)) * 2048 + h * 128 + dt * 16 + (l & 15)] =
            f2bf(yacc[dt][r] / lrow[r]);
      }
  }
}

// ---------------------------------------------------------------------- launch
extern "C" void kernel_launch(void* const* d_in, const int* in_sizes, int n_in,
                              void* d_out, int out_size, void* d_ws, size_t ws_size,
                              hipStream_t stream) {
  const float* x    = (const float*)d_in[0];
  const float* wqkv = (const float*)d_in[1];
  const float* wout = (const float*)d_in[2];
  float* out = (float*)d_out;

  unsigned short* ws  = (unsigned short*)d_ws;
  unsigned short* xb  = ws;                        // 4096*2048
  unsigned short* wqb = xb + (size_t)8388608;      // 6144*2048
  unsigned short* wob = wqb + (size_t)12582912;    // 2048*2048
  unsigned short* Qb  = wob + (size_t)4194304;     // [32,2048,128]
  unsigned short* Kb  = Qb + (size_t)8388608;      // [32,2048,128]
  unsigned short* Vtb = Kb + (size_t)8388608;      // [32,128,2048]
  unsigned short* Yb  = Vtb + (size_t)8388608;     // [4096,2048]

  cvt_bf16<<<1024, 256, 0, stream>>>(x, xb, 8388608 / 8);
  cvt_bf16<<<1024, 256, 0, stream>>>(wqkv, wqb, 12582912 / 8);
  cvt_bf16<<<512, 256, 0, stream>>>(wob == nullptr ? wout : wout, wob, 4194304 / 8);
  gemm_qkv8<<<384, 512, 0, stream>>>(xb, wqb, Qb, Kb, Vtb);
  attn_kernel<<<dim3(16, 32), 256, 0, stream>>>(Qb, Kb, Vtb, Yb);
  gemm_out<<<dim3(16, 32), 256, 0, stream>>>(Yb, wob, out);
}